// Round 6
// baseline (464.641 us; speedup 1.0000x reference)
//
#include <hip/hip_runtime.h>

#define BB 4
#define SS 2048
#define EE 512
#define HH 8
#define DHH 8
#define DVV 64   // H*DHH

#define NEG (-1e30f)

// ---------------- Kernel A: QKV projections, register-tiled GEMM ----------
// C[row, col] = sum_e X[row,e] * W[col/8, e, col%8];  X:[8192,512], C:[8192,64]
// grid (8192/64, 3), block 256. Thread tile 4x4, K-tile 64.
__global__ void proj_kernel(const float* __restrict__ q, const float* __restrict__ k,
                            const float* __restrict__ v,
                            const float* __restrict__ Wq, const float* __restrict__ Wk,
                            const float* __restrict__ Wv,
                            float* __restrict__ Qp, float* __restrict__ Kp,
                            float* __restrict__ Vp)
{
  const float* x; const float* W; float* outp;
  if (blockIdx.y == 0)      { x = q; W = Wq; outp = Qp; }
  else if (blockIdx.y == 1) { x = k; W = Wk; outp = Kp; }
  else                      { x = v; W = Wv; outp = Vp; }

  __shared__ float Xs[64][68];   // [k][row], stride 68: inner b128 reads 2-way/free
  __shared__ float Ws[64][68];   // [k][col]

  int t = threadIdx.x;
  int row0 = blockIdx.x * 64;
  int tr = t >> 4;               // 0..15 -> rows 4*tr..4*tr+3
  int tc = t & 15;               // 0..15 -> cols 4*tc..4*tc+3

  float acc[4][4];
  #pragma unroll
  for (int i = 0; i < 4; i++)
    #pragma unroll
    for (int j = 0; j < 4; j++) acc[i][j] = 0.f;

  for (int kt = 0; kt < EE/64; kt++) {
    __syncthreads();
    // stage X tile transposed: Xs[k][row] = x[row0+row][kt*64+k]
    #pragma unroll
    for (int it = 0; it < 4; it++) {
      int lin = t + 256*it;          // 0..1023
      int row = lin >> 4;            // 0..63
      int kq  = lin & 15;            // float4 along k
      float4 vv = *(const float4*)(x + (size_t)(row0+row)*EE + kt*64 + 4*kq);
      Xs[4*kq+0][row] = vv.x;
      Xs[4*kq+1][row] = vv.y;
      Xs[4*kq+2][row] = vv.z;
      Xs[4*kq+3][row] = vv.w;
    }
    // stage W tile: Ws[k][8h+d] = W[h][kt*64+k][d]
    #pragma unroll
    for (int it = 0; it < 4; it++) {
      int lin = t + 256*it;          // 0..1023
      int kk  = lin >> 4;            // 0..63
      int rem = lin & 15;
      int h   = rem >> 1;
      int dq  = rem & 1;
      float4 vv = *(const float4*)(W + (size_t)h*EE*DHH + (size_t)(kt*64+kk)*DHH + dq*4);
      *(float4*)&Ws[kk][h*8 + dq*4] = vv;
    }
    __syncthreads();

    #pragma unroll 8
    for (int kk = 0; kk < 64; kk++) {
      float4 a = *(const float4*)&Xs[kk][4*tr];
      float4 bq = *(const float4*)&Ws[kk][4*tc];
      float av[4] = {a.x, a.y, a.z, a.w};
      float bv[4] = {bq.x, bq.y, bq.z, bq.w};
      #pragma unroll
      for (int i = 0; i < 4; i++)
        #pragma unroll
        for (int j = 0; j < 4; j++) acc[i][j] += av[i] * bv[j];
    }
  }

  // store: col0 = 4*tc -> h = tc>>1, dbase = (tc&1)*4 (float4-aligned)
  int h = tc >> 1, dbase = (tc & 1) * 4;
  #pragma unroll
  for (int i = 0; i < 4; i++) {
    int row = row0 + 4*tr + i;
    int b = row >> 11, s = row & (SS - 1);
    float4 vv; vv.x = acc[i][0]; vv.y = acc[i][1]; vv.z = acc[i][2]; vv.w = acc[i][3];
    *(float4*)(outp + (((size_t)b*HH + h)*SS + s)*DHH + dbase) = vv;
  }
}

// ---------------- Kernel B: causal flash attention, 4 rows/thread ---------
// grid (S/64, H, B), block 256. tr=t&15 -> 4 rows; tcw=t>>4 -> cols tcw+16j.
__global__ void attn_kernel(const float* __restrict__ Qp, const float* __restrict__ Kp,
                            const float* __restrict__ Vp, float* __restrict__ O)
{
  int qb = blockIdx.x, h = blockIdx.y, b = blockIdx.z;
  const float* Qh = Qp + (((size_t)b*HH + h)*SS)*DHH;
  const float* Kh = Kp + (((size_t)b*HH + h)*SS)*DHH;
  const float* Vh = Vp + (((size_t)b*HH + h)*SS)*DHH;

  __shared__ float Ks[128*DHH];          // 4 KiB
  __shared__ float Vs[128*DHH];          // 4 KiB
  __shared__ float Ps[4*16*4*10];        // 10 KiB cross-wave partials

  int t = threadIdx.x;
  int tr  = t & 15;              // row group: rows 4*tr..4*tr+3
  int tcw = t >> 4;              // 0..15 column slot
  int row0 = qb*64 + 4*tr;

  float qreg[4][8];
  #pragma unroll
  for (int i = 0; i < 4; i++) {
    const float* qp = Qh + (size_t)(row0 + i) * DHH;
    *(float4*)&qreg[i][0] = *(const float4*)qp;
    *(float4*)&qreg[i][4] = *(const float4*)(qp + 4);
  }

  float m[4] = {NEG, NEG, NEG, NEG};
  float l[4] = {0.f, 0.f, 0.f, 0.f};
  float o[4][8];
  #pragma unroll
  for (int i = 0; i < 4; i++)
    #pragma unroll
    for (int d = 0; d < 8; d++) o[i][d] = 0.f;

  const float scale = 0.35355339059327373f;  // 1/sqrt(8)

  int nkt = (qb >> 1) + 1;
  for (int kt = 0; kt < nkt; kt++) {
    __syncthreads();
    ((float4*)Ks)[t] = ((const float4*)(Kh + (size_t)kt*128*DHH))[t];
    ((float4*)Vs)[t] = ((const float4*)(Vh + (size_t)kt*128*DHH))[t];
    __syncthreads();

    if (kt*128 + tcw <= row0 + 3) {   // thread has >=1 unmasked (row,col)
      float sc[8][4];
      float smax[4] = {NEG, NEG, NEG, NEG};
      #pragma unroll
      for (int j = 0; j < 8; j++) {
        int c = tcw + 16*j;
        int cg = kt*128 + c;
        float4 k0 = *(const float4*)&Ks[c*8];
        float4 k1 = *(const float4*)&Ks[c*8 + 4];
        #pragma unroll
        for (int i = 0; i < 4; i++) {
          float s = qreg[i][0]*k0.x + qreg[i][1]*k0.y + qreg[i][2]*k0.z + qreg[i][3]*k0.w
                  + qreg[i][4]*k1.x + qreg[i][5]*k1.y + qreg[i][6]*k1.z + qreg[i][7]*k1.w;
          s *= scale;
          s = (cg > row0 + i) ? NEG : s;
          sc[j][i] = s;
          smax[i] = fmaxf(smax[i], s);
        }
      }
      float mexp[4];
      #pragma unroll
      for (int i = 0; i < 4; i++) {
        float mnew = fmaxf(m[i], smax[i]);
        float alpha = __expf(m[i] - mnew);   // NEG->finite: 0; NEG->NEG: exp(0)=1 (l=0,o=0)
        l[i] *= alpha;
        #pragma unroll
        for (int d = 0; d < 8; d++) o[i][d] *= alpha;
        m[i] = mnew;
        mexp[i] = (mnew > -1e29f) ? mnew : 1e30f;  // inactive row -> p underflows to 0
      }
      #pragma unroll
      for (int j = 0; j < 8; j++) {
        int c = tcw + 16*j;
        float4 v0 = *(const float4*)&Vs[c*8];
        float4 v1 = *(const float4*)&Vs[c*8 + 4];
        #pragma unroll
        for (int i = 0; i < 4; i++) {
          float p = __expf(sc[j][i] - mexp[i]);
          l[i] += p;
          o[i][0] += p*v0.x; o[i][1] += p*v0.y; o[i][2] += p*v0.z; o[i][3] += p*v0.w;
          o[i][4] += p*v1.x; o[i][5] += p*v1.y; o[i][6] += p*v1.z; o[i][7] += p*v1.w;
        }
      }
    }
  }

  // intra-wave merge across the 4 column slots resident in this wave
  #pragma unroll
  for (int st = 16; st <= 32; st <<= 1) {
    #pragma unroll
    for (int i = 0; i < 4; i++) {
      float mo = __shfl_xor(m[i], st);
      float lo = __shfl_xor(l[i], st);
      float mm = fmaxf(m[i], mo);
      float a1 = __expf(m[i] - mm);   // NEG pairs -> exp(0)=1, harmless (l=0)
      float a2 = __expf(mo - mm);
      l[i] = l[i]*a1 + lo*a2;
      #pragma unroll
      for (int d = 0; d < 8; d++) {
        float od = __shfl_xor(o[i][d], st);
        o[i][d] = o[i][d]*a1 + od*a2;
      }
      m[i] = mm;
    }
  }

  // cross-wave: wave w, lanes 0..15 hold merged partials for rows 4*tr..4*tr+3
  int w = t >> 6;
  if ((t & 48) == 0) {
    #pragma unroll
    for (int i = 0; i < 4; i++) {
      float* ps = &Ps[((w*16 + tr)*4 + i)*10];
      ps[0] = m[i]; ps[1] = l[i];
      #pragma unroll
      for (int d = 0; d < 8; d++) ps[2+d] = o[i][d];
    }
  }
  __syncthreads();

  if (t < 64) {
    float M = NEG, L = 0.f, O8[8] = {0,0,0,0,0,0,0,0};
    #pragma unroll
    for (int ww = 0; ww < 4; ww++) {
      const float* ps = &Ps[(ww*64 + t)*10];
      float mo = ps[0], lo = ps[1];
      float mm = fmaxf(M, mo);
      float a1 = __expf(M - mm);
      float a2 = __expf(mo - mm);
      L = L*a1 + lo*a2;
      #pragma unroll
      for (int d = 0; d < 8; d++) O8[d] = O8[d]*a1 + ps[2+d]*a2;
      M = mm;
    }
    float inv = 1.0f / L;
    int qrow = qb*64 + t;
    float* dst = O + ((size_t)b*SS + qrow)*DVV + h*DHH;
    float4 w0, w1;
    w0.x = O8[0]*inv; w0.y = O8[1]*inv; w0.z = O8[2]*inv; w0.w = O8[3]*inv;
    w1.x = O8[4]*inv; w1.y = O8[5]*inv; w1.z = O8[6]*inv; w1.w = O8[7]*inv;
    *(float4*)dst = w0;
    *(float4*)(dst + 4) = w1;
  }
}

// ---------------- Kernel C: output projection, register-tiled GEMM --------
// out[row,e] = sum_d O[row,d]*Wo[d,e] + bo[e]; grid (8192/64, 512/128), block 256.
__global__ void outproj_kernel(const float* __restrict__ Oin, const float* __restrict__ Wo,
                               const float* __restrict__ bo, float* __restrict__ out)
{
  __shared__ float Os[64][68];   // [k][row] transposed
  int t = threadIdx.x;
  int row0 = blockIdx.x * 64;
  int col0 = blockIdx.y * 128;

  #pragma unroll
  for (int it = 0; it < 4; it++) {
    int lin = t + 256*it;
    int row = lin >> 4;
    int kq  = lin & 15;
    float4 vv = *(const float4*)(Oin + (size_t)(row0+row)*DVV + 4*kq);
    Os[4*kq+0][row] = vv.x;
    Os[4*kq+1][row] = vv.y;
    Os[4*kq+2][row] = vv.z;
    Os[4*kq+3][row] = vv.w;
  }
  __syncthreads();

  int rg = t >> 5;               // 0..7 -> rows 8*rg..8*rg+7
  int tc = t & 31;               // cols col0 + 4*tc .. +3
  const float* wp = Wo + col0 + 4*tc;
  float4 b4 = *(const float4*)(bo + col0 + 4*tc);

  float acc[8][4];
  #pragma unroll
  for (int r = 0; r < 8; r++) {
    acc[r][0] = b4.x; acc[r][1] = b4.y; acc[r][2] = b4.z; acc[r][3] = b4.w;
  }

  #pragma unroll 8
  for (int k = 0; k < DVV; k++) {
    float4 w = *(const float4*)(wp + (size_t)k*EE);   // coalesced, L2-hot
    float xr[8];
    *(float4*)&xr[0] = *(const float4*)&Os[k][8*rg];
    *(float4*)&xr[4] = *(const float4*)&Os[k][8*rg + 4];
    #pragma unroll
    for (int r = 0; r < 8; r++) {
      acc[r][0] += xr[r]*w.x;
      acc[r][1] += xr[r]*w.y;
      acc[r][2] += xr[r]*w.z;
      acc[r][3] += xr[r]*w.w;
    }
  }

  #pragma unroll
  for (int r = 0; r < 8; r++) {
    int row = row0 + 8*rg + r;
    float4 vv; vv.x = acc[r][0]; vv.y = acc[r][1]; vv.z = acc[r][2]; vv.w = acc[r][3];
    *(float4*)(out + (size_t)row*EE + col0 + 4*tc) = vv;
  }
}

extern "C" void kernel_launch(void* const* d_in, const int* in_sizes, int n_in,
                              void* d_out, int out_size, void* d_ws, size_t ws_size,
                              hipStream_t stream) {
  // Size-based input identification: q/k/v=4194304, Wq/Wk/Wv/Wo=32768 in dict
  // order, bo=512. padding_mask (16777216) / decoder_mask (1) skipped.
  const void* qkv[3] = {nullptr, nullptr, nullptr};
  const void* Wlist[4] = {nullptr, nullptr, nullptr, nullptr};
  const void* bo = nullptr;
  int nqkv = 0, nw = 0;
  for (int i = 0; i < n_in; i++) {
    int sz = in_sizes[i];
    if (sz == BB*SS*EE)            { if (nqkv < 3) qkv[nqkv] = d_in[i]; nqkv++; }
    else if (sz == HH*EE*DHH)      { if (nw < 4) Wlist[nw] = d_in[i]; nw++; }
    else if (sz == EE)             { bo = d_in[i]; }
  }
  float* out = (float*)d_out;   // reference output dtype is float32

  // workspace (f32): Qp/Kp/Vp [B,H,S,8] (2MB each), O [B,S,64] (2MB)
  float* Qp = (float*)d_ws;
  float* Kp = Qp + (size_t)BB*HH*SS*DHH;
  float* Vp = Kp + (size_t)BB*HH*SS*DHH;
  float* O  = Vp + (size_t)BB*HH*SS*DHH;

  dim3 gA(BB*SS/64, 3, 1);
  proj_kernel<<<gA, 256, 0, stream>>>((const float*)qkv[0], (const float*)qkv[1],
                                      (const float*)qkv[2],
                                      (const float*)Wlist[0], (const float*)Wlist[1],
                                      (const float*)Wlist[2], Qp, Kp, Vp);

  dim3 gB(SS/64, HH, BB);
  attn_kernel<<<gB, 256, 0, stream>>>(Qp, Kp, Vp, O);

  dim3 gC(BB*SS/64, EE/128, 1);
  outproj_kernel<<<gC, 256, 0, stream>>>(O, (const float*)Wlist[3],
                                         (const float*)bo, out);
}

// Round 7
// 283.659 us; speedup vs baseline: 1.6380x; 1.6380x over previous
//
#include <hip/hip_runtime.h>

#define BB 4
#define SS 2048
#define EE 512
#define HH 8
#define DHH 8
#define DVV 64   // H*DHH

#define NEG (-1e30f)

// ---------------- Kernel A: QKV projections, register-tiled GEMM ----------
// C[row, col] = sum_e X[row,e] * W[col/8, e, col%8];  X:[8192,512], C:[8192,64]
// grid (8192/64, 3), block 256. Thread tile 4x4, K-tile 64.
__global__ __launch_bounds__(256)
void proj_kernel(const float* __restrict__ q, const float* __restrict__ k,
                 const float* __restrict__ v,
                 const float* __restrict__ Wq, const float* __restrict__ Wk,
                 const float* __restrict__ Wv,
                 float* __restrict__ Qp, float* __restrict__ Kp,
                 float* __restrict__ Vp)
{
  const float* x; const float* W; float* outp;
  if (blockIdx.y == 0)      { x = q; W = Wq; outp = Qp; }
  else if (blockIdx.y == 1) { x = k; W = Wk; outp = Kp; }
  else                      { x = v; W = Wv; outp = Vp; }

  __shared__ float Xs[64][68];   // [k][row]
  __shared__ float Ws[64][68];   // [k][col]

  int t = threadIdx.x;
  int row0 = blockIdx.x * 64;
  int tr = t >> 4;               // 0..15 -> rows 4*tr..4*tr+3
  int tc = t & 15;               // 0..15 -> cols 4*tc..4*tc+3

  float acc[4][4];
  #pragma unroll
  for (int i = 0; i < 4; i++)
    #pragma unroll
    for (int j = 0; j < 4; j++) acc[i][j] = 0.f;

  for (int kt = 0; kt < EE/64; kt++) {
    __syncthreads();
    // stage X tile transposed: Xs[k][row] = x[row0+row][kt*64+k]
    // lane map row=t>>2, kq=4*it+(t&3): LDS write banks 2-way only (free)
    {
      int row = t >> 2;
      #pragma unroll
      for (int it = 0; it < 4; it++) {
        int kq = 4*it + (t & 3);
        float4 vv = *(const float4*)(x + (size_t)(row0+row)*EE + kt*64 + 4*kq);
        Xs[4*kq+0][row] = vv.x;
        Xs[4*kq+1][row] = vv.y;
        Xs[4*kq+2][row] = vv.z;
        Xs[4*kq+3][row] = vv.w;
      }
    }
    // stage W tile: Ws[k][8h+d] = W[h][kt*64+k][d]
    #pragma unroll
    for (int it = 0; it < 4; it++) {
      int lin = t + 256*it;          // 0..1023
      int kk  = lin >> 4;            // 0..63
      int rem = lin & 15;
      int h   = rem >> 1;
      int dq  = rem & 1;
      float4 vv = *(const float4*)(W + (size_t)h*EE*DHH + (size_t)(kt*64+kk)*DHH + dq*4);
      *(float4*)&Ws[kk][h*8 + dq*4] = vv;
    }
    __syncthreads();

    #pragma unroll 8
    for (int kk = 0; kk < 64; kk++) {
      float4 a = *(const float4*)&Xs[kk][4*tr];
      float4 bq = *(const float4*)&Ws[kk][4*tc];
      float av[4] = {a.x, a.y, a.z, a.w};
      float bv[4] = {bq.x, bq.y, bq.z, bq.w};
      #pragma unroll
      for (int i = 0; i < 4; i++)
        #pragma unroll
        for (int j = 0; j < 4; j++) acc[i][j] += av[i] * bv[j];
    }
  }

  // store: col0 = 4*tc -> h = tc>>1, dbase = (tc&1)*4 (float4-aligned)
  int h = tc >> 1, dbase = (tc & 1) * 4;
  #pragma unroll
  for (int i = 0; i < 4; i++) {
    int row = row0 + 4*tr + i;
    int b = row >> 11, s = row & (SS - 1);
    float4 vv; vv.x = acc[i][0]; vv.y = acc[i][1]; vv.z = acc[i][2]; vv.w = acc[i][3];
    *(float4*)(outp + (((size_t)b*HH + h)*SS + s)*DHH + dbase) = vv;
  }
}

// ---------------- Kernel B: causal flash attention ------------------------
// grid (S/64, H, B), block 256. 2 rows/thread (r2=t&31), 8 col slots
// (tcw=t>>5), cols c = tcw + 8*j. Chunked scores sc[8][2] -> ~80 VGPRs.
__global__ __launch_bounds__(256, 2)
void attn_kernel(const float* __restrict__ Qp, const float* __restrict__ Kp,
                 const float* __restrict__ Vp, float* __restrict__ O)
{
  int qb = blockIdx.x, h = blockIdx.y, b = blockIdx.z;
  const float* Qh = Qp + (((size_t)b*HH + h)*SS)*DHH;
  const float* Kh = Kp + (((size_t)b*HH + h)*SS)*DHH;
  const float* Vh = Vp + (((size_t)b*HH + h)*SS)*DHH;

  __shared__ float Ks[128*DHH];          // 4 KiB
  __shared__ float Vs[128*DHH];          // 4 KiB
  __shared__ float Ps[4*64*10];          // 10 KiB cross-wave partials

  int t = threadIdx.x;
  int r2  = t & 31;              // rows 2*r2, 2*r2+1
  int tcw = t >> 5;              // 0..7 column slot
  int row0t = qb*64 + 2*r2;

  float qreg[2][8];
  #pragma unroll
  for (int i = 0; i < 2; i++) {
    const float* qp = Qh + (size_t)(row0t + i) * DHH;
    *(float4*)&qreg[i][0] = *(const float4*)qp;
    *(float4*)&qreg[i][4] = *(const float4*)(qp + 4);
  }

  float m[2] = {NEG, NEG};
  float l[2] = {0.f, 0.f};
  float o[2][8];
  #pragma unroll
  for (int i = 0; i < 2; i++)
    #pragma unroll
    for (int d = 0; d < 8; d++) o[i][d] = 0.f;

  const float scale = 0.35355339059327373f;  // 1/sqrt(8)

  int nkt = (qb >> 1) + 1;
  for (int kt = 0; kt < nkt; kt++) {
    __syncthreads();
    ((float4*)Ks)[t] = ((const float4*)(Kh + (size_t)kt*128*DHH))[t];
    ((float4*)Vs)[t] = ((const float4*)(Vh + (size_t)kt*128*DHH))[t];
    __syncthreads();

    for (int j0 = 0; j0 < 16; j0 += 8) {
      if (kt*128 + tcw + 8*j0 > row0t + 1) break;   // monotone in j0

      float sc[8][2];
      float smax[2] = {NEG, NEG};
      #pragma unroll
      for (int j = 0; j < 8; j++) {
        int c = tcw + 8*(j0 + j);
        int cg = kt*128 + c;
        float4 k0 = *(const float4*)&Ks[c*8];
        float4 k1 = *(const float4*)&Ks[c*8 + 4];
        #pragma unroll
        for (int i = 0; i < 2; i++) {
          float s = qreg[i][0]*k0.x + qreg[i][1]*k0.y + qreg[i][2]*k0.z + qreg[i][3]*k0.w
                  + qreg[i][4]*k1.x + qreg[i][5]*k1.y + qreg[i][6]*k1.z + qreg[i][7]*k1.w;
          s *= scale;
          s = (cg > row0t + i) ? NEG : s;
          sc[j][i] = s;
          smax[i] = fmaxf(smax[i], s);
        }
      }
      float mexp[2];
      #pragma unroll
      for (int i = 0; i < 2; i++) {
        float mnew = fmaxf(m[i], smax[i]);
        float alpha = __expf(m[i] - mnew);   // NEG->NEG: exp(0)=1, l=o=0 harmless
        l[i] *= alpha;
        #pragma unroll
        for (int d = 0; d < 8; d++) o[i][d] *= alpha;
        m[i] = mnew;
        mexp[i] = (mnew > -1e29f) ? mnew : 1e30f;  // inactive row -> p = 0
      }
      #pragma unroll
      for (int j = 0; j < 8; j++) {
        int c = tcw + 8*(j0 + j);
        float4 v0 = *(const float4*)&Vs[c*8];
        float4 v1 = *(const float4*)&Vs[c*8 + 4];
        #pragma unroll
        for (int i = 0; i < 2; i++) {
          float p = __expf(sc[j][i] - mexp[i]);
          l[i] += p;
          o[i][0] += p*v0.x; o[i][1] += p*v0.y; o[i][2] += p*v0.z; o[i][3] += p*v0.w;
          o[i][4] += p*v1.x; o[i][5] += p*v1.y; o[i][6] += p*v1.z; o[i][7] += p*v1.w;
        }
      }
    }
  }

  // intra-wave merge: partner col-slot lives at lane t^32 (same r2)
  #pragma unroll
  for (int i = 0; i < 2; i++) {
    float mo = __shfl_xor(m[i], 32);
    float lo = __shfl_xor(l[i], 32);
    float mm = fmaxf(m[i], mo);
    float a1 = __expf(m[i] - mm);
    float a2 = __expf(mo - mm);
    l[i] = l[i]*a1 + lo*a2;
    #pragma unroll
    for (int d = 0; d < 8; d++) {
      float od = __shfl_xor(o[i][d], 32);
      o[i][d] = o[i][d]*a1 + od*a2;
    }
    m[i] = mm;
  }

  // cross-wave: 4 partials per row, via LDS
  int w = t >> 6;
  if ((t & 32) == 0) {
    #pragma unroll
    for (int i = 0; i < 2; i++) {
      float* ps = &Ps[(w*64 + 2*r2 + i)*10];
      ps[0] = m[i]; ps[1] = l[i];
      #pragma unroll
      for (int d = 0; d < 8; d++) ps[2+d] = o[i][d];
    }
  }
  __syncthreads();

  if (t < 64) {
    float M = NEG, L = 0.f, O8[8] = {0,0,0,0,0,0,0,0};
    #pragma unroll
    for (int ww = 0; ww < 4; ww++) {
      const float* ps = &Ps[(ww*64 + t)*10];
      float mo = ps[0], lo = ps[1];
      float mm = fmaxf(M, mo);
      float a1 = __expf(M - mm);
      float a2 = __expf(mo - mm);
      L = L*a1 + lo*a2;
      #pragma unroll
      for (int d = 0; d < 8; d++) O8[d] = O8[d]*a1 + ps[2+d]*a2;
      M = mm;
    }
    float inv = 1.0f / L;
    int qrow = qb*64 + t;
    float* dst = O + ((size_t)b*SS + qrow)*DVV + h*DHH;
    float4 w0, w1;
    w0.x = O8[0]*inv; w0.y = O8[1]*inv; w0.z = O8[2]*inv; w0.w = O8[3]*inv;
    w1.x = O8[4]*inv; w1.y = O8[5]*inv; w1.z = O8[6]*inv; w1.w = O8[7]*inv;
    *(float4*)dst = w0;
    *(float4*)(dst + 4) = w1;
  }
}

// ---------------- Kernel C: output projection, register-tiled GEMM --------
// out[row,e] = sum_d O[row,d]*Wo[d,e] + bo[e]; grid (8192/64, 512/128), block 256.
__global__ __launch_bounds__(256)
void outproj_kernel(const float* __restrict__ Oin, const float* __restrict__ Wo,
                    const float* __restrict__ bo, float* __restrict__ out)
{
  __shared__ float Os[64][68];   // [k][row] transposed
  int t = threadIdx.x;
  int row0 = blockIdx.x * 64;
  int col0 = blockIdx.y * 128;

  {
    int row = t >> 2;
    #pragma unroll
    for (int it = 0; it < 4; it++) {
      int kq = 4*it + (t & 3);
      float4 vv = *(const float4*)(Oin + (size_t)(row0+row)*DVV + 4*kq);
      Os[4*kq+0][row] = vv.x;
      Os[4*kq+1][row] = vv.y;
      Os[4*kq+2][row] = vv.z;
      Os[4*kq+3][row] = vv.w;
    }
  }
  __syncthreads();

  int rg = t >> 5;               // 0..7 -> rows 8*rg..8*rg+7
  int tc = t & 31;               // cols col0 + 4*tc .. +3
  const float* wp = Wo + col0 + 4*tc;
  float4 b4 = *(const float4*)(bo + col0 + 4*tc);

  float acc[8][4];
  #pragma unroll
  for (int r = 0; r < 8; r++) {
    acc[r][0] = b4.x; acc[r][1] = b4.y; acc[r][2] = b4.z; acc[r][3] = b4.w;
  }

  #pragma unroll 8
  for (int k = 0; k < DVV; k++) {
    float4 w = *(const float4*)(wp + (size_t)k*EE);   // coalesced, L2-hot
    float xr[8];
    *(float4*)&xr[0] = *(const float4*)&Os[k][8*rg];
    *(float4*)&xr[4] = *(const float4*)&Os[k][8*rg + 4];
    #pragma unroll
    for (int r = 0; r < 8; r++) {
      acc[r][0] += xr[r]*w.x;
      acc[r][1] += xr[r]*w.y;
      acc[r][2] += xr[r]*w.z;
      acc[r][3] += xr[r]*w.w;
    }
  }

  #pragma unroll
  for (int r = 0; r < 8; r++) {
    int row = row0 + 8*rg + r;
    float4 vv; vv.x = acc[r][0]; vv.y = acc[r][1]; vv.z = acc[r][2]; vv.w = acc[r][3];
    *(float4*)(out + (size_t)row*EE + col0 + 4*tc) = vv;
  }
}

extern "C" void kernel_launch(void* const* d_in, const int* in_sizes, int n_in,
                              void* d_out, int out_size, void* d_ws, size_t ws_size,
                              hipStream_t stream) {
  // Size-based input identification: q/k/v=4194304, Wq/Wk/Wv/Wo=32768 in dict
  // order, bo=512. padding_mask (16777216) / decoder_mask (1) skipped.
  const void* qkv[3] = {nullptr, nullptr, nullptr};
  const void* Wlist[4] = {nullptr, nullptr, nullptr, nullptr};
  const void* bo = nullptr;
  int nqkv = 0, nw = 0;
  for (int i = 0; i < n_in; i++) {
    int sz = in_sizes[i];
    if (sz == BB*SS*EE)            { if (nqkv < 3) qkv[nqkv] = d_in[i]; nqkv++; }
    else if (sz == HH*EE*DHH)      { if (nw < 4) Wlist[nw] = d_in[i]; nw++; }
    else if (sz == EE)             { bo = d_in[i]; }
  }
  float* out = (float*)d_out;   // reference output dtype is float32

  // workspace (f32): Qp/Kp/Vp [B,H,S,8] (2MB each), O [B,S,64] (2MB)
  float* Qp = (float*)d_ws;
  float* Kp = Qp + (size_t)BB*HH*SS*DHH;
  float* Vp = Kp + (size_t)BB*HH*SS*DHH;
  float* O  = Vp + (size_t)BB*HH*SS*DHH;

  dim3 gA(BB*SS/64, 3, 1);
  proj_kernel<<<gA, 256, 0, stream>>>((const float*)qkv[0], (const float*)qkv[1],
                                      (const float*)qkv[2],
                                      (const float*)Wlist[0], (const float*)Wlist[1],
                                      (const float*)Wlist[2], Qp, Kp, Vp);

  dim3 gB(SS/64, HH, BB);
  attn_kernel<<<gB, 256, 0, stream>>>(Qp, Kp, Vp, O);

  dim3 gC(BB*SS/64, EE/128, 1);
  outproj_kernel<<<gC, 256, 0, stream>>>(O, (const float*)Wlist[3],
                                         (const float*)bo, out);
}

// Round 8
// 237.126 us; speedup vs baseline: 1.9595x; 1.1962x over previous
//
#include <hip/hip_runtime.h>

#define BB 4
#define SS 2048
#define EE 512
#define HH 8
#define DHH 8
#define DVV 64   // H*DHH

#define NEG (-1e30f)

// ---------------- Kernel A: QKV projections, register-tiled GEMM ----------
// C[row, col] = sum_e X[row,e] * W[col/8, e, col%8];  X:[8192,512], C:[8192,64]
// grid (8192/64, 3), block 256. Thread tile 4x4, K-tile 64.
__global__ __launch_bounds__(256)
void proj_kernel(const float* __restrict__ q, const float* __restrict__ k,
                 const float* __restrict__ v,
                 const float* __restrict__ Wq, const float* __restrict__ Wk,
                 const float* __restrict__ Wv,
                 float* __restrict__ Qp, float* __restrict__ Kp,
                 float* __restrict__ Vp)
{
  const float* x; const float* W; float* outp;
  if (blockIdx.y == 0)      { x = q; W = Wq; outp = Qp; }
  else if (blockIdx.y == 1) { x = k; W = Wk; outp = Kp; }
  else                      { x = v; W = Wv; outp = Vp; }

  __shared__ float Xs[64][68];   // [k][row]
  __shared__ float Ws[64][68];   // [k][col]

  int t = threadIdx.x;
  int row0 = blockIdx.x * 64;
  int tr = t >> 4;               // 0..15 -> rows 4*tr..4*tr+3
  int tc = t & 15;               // 0..15 -> cols 4*tc..4*tc+3

  float acc[4][4];
  #pragma unroll
  for (int i = 0; i < 4; i++)
    #pragma unroll
    for (int j = 0; j < 4; j++) acc[i][j] = 0.f;

  for (int kt = 0; kt < EE/64; kt++) {
    __syncthreads();
    // stage X tile transposed: Xs[k][row] = x[row0+row][kt*64+k]
    {
      int row = t >> 2;
      #pragma unroll
      for (int it = 0; it < 4; it++) {
        int kq = 4*it + (t & 3);
        float4 vv = *(const float4*)(x + (size_t)(row0+row)*EE + kt*64 + 4*kq);
        Xs[4*kq+0][row] = vv.x;
        Xs[4*kq+1][row] = vv.y;
        Xs[4*kq+2][row] = vv.z;
        Xs[4*kq+3][row] = vv.w;
      }
    }
    // stage W tile: Ws[k][8h+d] = W[h][kt*64+k][d]
    #pragma unroll
    for (int it = 0; it < 4; it++) {
      int lin = t + 256*it;          // 0..1023
      int kk  = lin >> 4;            // 0..63
      int rem = lin & 15;
      int h   = rem >> 1;
      int dq  = rem & 1;
      float4 vv = *(const float4*)(W + (size_t)h*EE*DHH + (size_t)(kt*64+kk)*DHH + dq*4);
      *(float4*)&Ws[kk][h*8 + dq*4] = vv;
    }
    __syncthreads();

    #pragma unroll 8
    for (int kk = 0; kk < 64; kk++) {
      float4 a = *(const float4*)&Xs[kk][4*tr];
      float4 bq = *(const float4*)&Ws[kk][4*tc];
      float av[4] = {a.x, a.y, a.z, a.w};
      float bv[4] = {bq.x, bq.y, bq.z, bq.w};
      #pragma unroll
      for (int i = 0; i < 4; i++)
        #pragma unroll
        for (int j = 0; j < 4; j++) acc[i][j] += av[i] * bv[j];
    }
  }

  int h = tc >> 1, dbase = (tc & 1) * 4;
  #pragma unroll
  for (int i = 0; i < 4; i++) {
    int row = row0 + 4*tr + i;
    int b = row >> 11, s = row & (SS - 1);
    float4 vv; vv.x = acc[i][0]; vv.y = acc[i][1]; vv.z = acc[i][2]; vv.w = acc[i][3];
    *(float4*)(outp + (((size_t)b*HH + h)*SS + s)*DHH + dbase) = vv;
  }
}

// ---------------- Kernel B: causal flash attention, load-balanced ---------
// grid (16, H, B), block 256. Block handles q-tile pair (bx, 31-bx) ->
// constant ~17 K-tiles/block; 512 blocks = 2/CU resident for whole kernel.
// 2 rows/thread (r2=t&31), 8 col slots (tcw=t>>5), cols c = tcw + 8j.
// Full tiles (kt < qb>>1): mask-free path, single softmax update per tile.
__global__ __launch_bounds__(256, 2)
void attn_kernel(const float* __restrict__ Qp, const float* __restrict__ Kp,
                 const float* __restrict__ Vp, float* __restrict__ O)
{
  int bx = blockIdx.x, h = blockIdx.y, b = blockIdx.z;
  const float* Qh = Qp + (((size_t)b*HH + h)*SS)*DHH;
  const float* Kh = Kp + (((size_t)b*HH + h)*SS)*DHH;
  const float* Vh = Vp + (((size_t)b*HH + h)*SS)*DHH;

  __shared__ float Ks[128*DHH];          // 4 KiB
  __shared__ float Vs[128*DHH];          // 4 KiB
  __shared__ float Ps[4*64*10];          // 10 KiB cross-wave partials

  int t = threadIdx.x;
  int r2  = t & 31;              // rows 2*r2, 2*r2+1
  int tcw = t >> 5;              // 0..7 column slot
  const float scale = 0.35355339059327373f;  // 1/sqrt(8)

  for (int pass = 0; pass < 2; pass++) {
    int qb = (pass == 0) ? bx : (31 - bx);
    int row0t = qb*64 + 2*r2;

    float qreg[2][8];
    #pragma unroll
    for (int i = 0; i < 2; i++) {
      const float* qp = Qh + (size_t)(row0t + i) * DHH;
      *(float4*)&qreg[i][0] = *(const float4*)qp;
      *(float4*)&qreg[i][4] = *(const float4*)(qp + 4);
    }

    float m[2] = {NEG, NEG};
    float l[2] = {0.f, 0.f};
    float o[2][8];
    #pragma unroll
    for (int i = 0; i < 2; i++)
      #pragma unroll
      for (int d = 0; d < 8; d++) o[i][d] = 0.f;

    int ktd = qb >> 1;
    for (int kt = 0; kt <= ktd; kt++) {
      __syncthreads();
      ((float4*)Ks)[t] = ((const float4*)(Kh + (size_t)kt*128*DHH))[t];
      ((float4*)Vs)[t] = ((const float4*)(Vh + (size_t)kt*128*DHH))[t];
      __syncthreads();

      if (kt < ktd) {
        // ---- full tile: every (row,col) valid, no masks ----
        float sc[16][2];
        float smax[2] = {NEG, NEG};
        #pragma unroll
        for (int j = 0; j < 16; j++) {
          int c = tcw + 8*j;
          float4 k0 = *(const float4*)&Ks[c*8];
          float4 k1 = *(const float4*)&Ks[c*8 + 4];
          #pragma unroll
          for (int i = 0; i < 2; i++) {
            float s = qreg[i][0]*k0.x + qreg[i][1]*k0.y + qreg[i][2]*k0.z + qreg[i][3]*k0.w
                    + qreg[i][4]*k1.x + qreg[i][5]*k1.y + qreg[i][6]*k1.z + qreg[i][7]*k1.w;
            s *= scale;
            sc[j][i] = s;
            smax[i] = fmaxf(smax[i], s);
          }
        }
        #pragma unroll
        for (int i = 0; i < 2; i++) {
          float mnew = fmaxf(m[i], smax[i]);
          float alpha = __expf(m[i] - mnew);   // first tile: exp(-huge)=0
          l[i] *= alpha;
          #pragma unroll
          for (int d = 0; d < 8; d++) o[i][d] *= alpha;
          m[i] = mnew;
        }
        #pragma unroll
        for (int j = 0; j < 16; j++) {
          int c = tcw + 8*j;
          float4 v0 = *(const float4*)&Vs[c*8];
          float4 v1 = *(const float4*)&Vs[c*8 + 4];
          #pragma unroll
          for (int i = 0; i < 2; i++) {
            float p = __expf(sc[j][i] - m[i]);
            l[i] += p;
            o[i][0] += p*v0.x; o[i][1] += p*v0.y; o[i][2] += p*v0.z; o[i][3] += p*v0.w;
            o[i][4] += p*v1.x; o[i][5] += p*v1.y; o[i][6] += p*v1.z; o[i][7] += p*v1.w;
          }
        }
      } else {
        // ---- diagonal tile: masked, chunked ----
        for (int j0 = 0; j0 < 16; j0 += 8) {
          if (kt*128 + tcw + 8*j0 > row0t + 1) break;   // monotone in j0

          float sc[8][2];
          float smax[2] = {NEG, NEG};
          #pragma unroll
          for (int j = 0; j < 8; j++) {
            int c = tcw + 8*(j0 + j);
            int cg = kt*128 + c;
            float4 k0 = *(const float4*)&Ks[c*8];
            float4 k1 = *(const float4*)&Ks[c*8 + 4];
            #pragma unroll
            for (int i = 0; i < 2; i++) {
              float s = qreg[i][0]*k0.x + qreg[i][1]*k0.y + qreg[i][2]*k0.z + qreg[i][3]*k0.w
                      + qreg[i][4]*k1.x + qreg[i][5]*k1.y + qreg[i][6]*k1.z + qreg[i][7]*k1.w;
              s *= scale;
              s = (cg > row0t + i) ? NEG : s;
              sc[j][i] = s;
              smax[i] = fmaxf(smax[i], s);
            }
          }
          float mexp[2];
          #pragma unroll
          for (int i = 0; i < 2; i++) {
            float mnew = fmaxf(m[i], smax[i]);
            float alpha = __expf(m[i] - mnew);
            l[i] *= alpha;
            #pragma unroll
            for (int d = 0; d < 8; d++) o[i][d] *= alpha;
            m[i] = mnew;
            mexp[i] = (mnew > -1e29f) ? mnew : 1e30f;  // inactive row -> p = 0
          }
          #pragma unroll
          for (int j = 0; j < 8; j++) {
            int c = tcw + 8*(j0 + j);
            float4 v0 = *(const float4*)&Vs[c*8];
            float4 v1 = *(const float4*)&Vs[c*8 + 4];
            #pragma unroll
            for (int i = 0; i < 2; i++) {
              float p = __expf(sc[j][i] - mexp[i]);
              l[i] += p;
              o[i][0] += p*v0.x; o[i][1] += p*v0.y; o[i][2] += p*v0.z; o[i][3] += p*v0.w;
              o[i][4] += p*v1.x; o[i][5] += p*v1.y; o[i][6] += p*v1.z; o[i][7] += p*v1.w;
            }
          }
        }
      }
    }

    // intra-wave merge: partner col-slot at lane t^32 (same r2)
    #pragma unroll
    for (int i = 0; i < 2; i++) {
      float mo = __shfl_xor(m[i], 32);
      float lo = __shfl_xor(l[i], 32);
      float mm = fmaxf(m[i], mo);
      float a1 = __expf(m[i] - mm);
      float a2 = __expf(mo - mm);
      l[i] = l[i]*a1 + lo*a2;
      #pragma unroll
      for (int d = 0; d < 8; d++) {
        float od = __shfl_xor(o[i][d], 32);
        o[i][d] = o[i][d]*a1 + od*a2;
      }
      m[i] = mm;
    }

    // cross-wave: 4 partials per row, via LDS (write-own, barrier, read)
    int w = t >> 6;
    if ((t & 32) == 0) {
      #pragma unroll
      for (int i = 0; i < 2; i++) {
        float* ps = &Ps[(w*64 + 2*r2 + i)*10];
        ps[0] = m[i]; ps[1] = l[i];
        #pragma unroll
        for (int d = 0; d < 8; d++) ps[2+d] = o[i][d];
      }
    }
    __syncthreads();

    if (t < 64) {
      float M = NEG, L = 0.f, O8[8] = {0,0,0,0,0,0,0,0};
      #pragma unroll
      for (int ww = 0; ww < 4; ww++) {
        const float* ps = &Ps[(ww*64 + t)*10];
        float mo = ps[0], lo = ps[1];
        float mm = fmaxf(M, mo);
        float a1 = __expf(M - mm);
        float a2 = __expf(mo - mm);
        L = L*a1 + lo*a2;
        #pragma unroll
        for (int d = 0; d < 8; d++) O8[d] = O8[d]*a1 + ps[2+d]*a2;
        M = mm;
      }
      float inv = 1.0f / L;
      int qrow = qb*64 + t;
      float* dst = O + ((size_t)b*SS + qrow)*DVV + h*DHH;
      float4 w0, w1;
      w0.x = O8[0]*inv; w0.y = O8[1]*inv; w0.z = O8[2]*inv; w0.w = O8[3]*inv;
      w1.x = O8[4]*inv; w1.y = O8[5]*inv; w1.z = O8[6]*inv; w1.w = O8[7]*inv;
      *(float4*)dst = w0;
      *(float4*)(dst + 4) = w1;
    }
    __syncthreads();   // protect Ps/Ks/Vs before next pass re-stages
  }
}

// ---------------- Kernel C: output projection, register-tiled GEMM --------
// out[row,e] = sum_d O[row,d]*Wo[d,e] + bo[e]; grid (8192/64, 512/128), block 256.
__global__ __launch_bounds__(256)
void outproj_kernel(const float* __restrict__ Oin, const float* __restrict__ Wo,
                    const float* __restrict__ bo, float* __restrict__ out)
{
  __shared__ float Os[64][68];   // [k][row] transposed
  int t = threadIdx.x;
  int row0 = blockIdx.x * 64;
  int col0 = blockIdx.y * 128;

  {
    int row = t >> 2;
    #pragma unroll
    for (int it = 0; it < 4; it++) {
      int kq = 4*it + (t & 3);
      float4 vv = *(const float4*)(Oin + (size_t)(row0+row)*DVV + 4*kq);
      Os[4*kq+0][row] = vv.x;
      Os[4*kq+1][row] = vv.y;
      Os[4*kq+2][row] = vv.z;
      Os[4*kq+3][row] = vv.w;
    }
  }
  __syncthreads();

  int rg = t >> 5;               // 0..7 -> rows 8*rg..8*rg+7
  int tc = t & 31;               // cols col0 + 4*tc .. +3
  const float* wp = Wo + col0 + 4*tc;
  float4 b4 = *(const float4*)(bo + col0 + 4*tc);

  float acc[8][4];
  #pragma unroll
  for (int r = 0; r < 8; r++) {
    acc[r][0] = b4.x; acc[r][1] = b4.y; acc[r][2] = b4.z; acc[r][3] = b4.w;
  }

  #pragma unroll 8
  for (int k = 0; k < DVV; k++) {
    float4 w = *(const float4*)(wp + (size_t)k*EE);   // coalesced, L2-hot
    float xr[8];
    *(float4*)&xr[0] = *(const float4*)&Os[k][8*rg];
    *(float4*)&xr[4] = *(const float4*)&Os[k][8*rg + 4];
    #pragma unroll
    for (int r = 0; r < 8; r++) {
      acc[r][0] += xr[r]*w.x;
      acc[r][1] += xr[r]*w.y;
      acc[r][2] += xr[r]*w.z;
      acc[r][3] += xr[r]*w.w;
    }
  }

  #pragma unroll
  for (int r = 0; r < 8; r++) {
    int row = row0 + 8*rg + r;
    float4 vv; vv.x = acc[r][0]; vv.y = acc[r][1]; vv.z = acc[r][2]; vv.w = acc[r][3];
    *(float4*)(out + (size_t)row*EE + col0 + 4*tc) = vv;
  }
}

extern "C" void kernel_launch(void* const* d_in, const int* in_sizes, int n_in,
                              void* d_out, int out_size, void* d_ws, size_t ws_size,
                              hipStream_t stream) {
  // Size-based input identification: q/k/v=4194304, Wq/Wk/Wv/Wo=32768 in dict
  // order, bo=512. padding_mask (16777216) / decoder_mask (1) skipped.
  const void* qkv[3] = {nullptr, nullptr, nullptr};
  const void* Wlist[4] = {nullptr, nullptr, nullptr, nullptr};
  const void* bo = nullptr;
  int nqkv = 0, nw = 0;
  for (int i = 0; i < n_in; i++) {
    int sz = in_sizes[i];
    if (sz == BB*SS*EE)            { if (nqkv < 3) qkv[nqkv] = d_in[i]; nqkv++; }
    else if (sz == HH*EE*DHH)      { if (nw < 4) Wlist[nw] = d_in[i]; nw++; }
    else if (sz == EE)             { bo = d_in[i]; }
  }
  float* out = (float*)d_out;   // reference output dtype is float32

  // workspace (f32): Qp/Kp/Vp [B,H,S,8] (2MB each), O [B,S,64] (2MB)
  float* Qp = (float*)d_ws;
  float* Kp = Qp + (size_t)BB*HH*SS*DHH;
  float* Vp = Kp + (size_t)BB*HH*SS*DHH;
  float* O  = Vp + (size_t)BB*HH*SS*DHH;

  dim3 gA(BB*SS/64, 3, 1);
  proj_kernel<<<gA, 256, 0, stream>>>((const float*)qkv[0], (const float*)qkv[1],
                                      (const float*)qkv[2],
                                      (const float*)Wlist[0], (const float*)Wlist[1],
                                      (const float*)Wlist[2], Qp, Kp, Vp);

  dim3 gB(16, HH, BB);
  attn_kernel<<<gB, 256, 0, stream>>>(Qp, Kp, Vp, O);

  dim3 gC(BB*SS/64, EE/128, 1);
  outproj_kernel<<<gC, 256, 0, stream>>>(O, (const float*)Wlist[3],
                                         (const float*)bo, out);
}